// Round 1
// baseline (497.745 us; speedup 1.0000x reference)
//
#include <hip/hip_runtime.h>

#define T_STEPS 512
#define BATCH   128
#define DIN     256
#define HID     256
#define WPLD    (DIN + HID)   // 512, leading dim of Wp rows

// ---------------------------------------------------------------------------
// Kernel 1: proj_x[b][t][q] = sum_{d<256} x[t,b,d] * Wp[q,d]
// Grid: (T*B/4) blocks x 256 threads; each wave handles one (t,b) row.
// Lane scheme: q = lane>>3 owns output q; c8 = lane&7 covers a 32-float chunk.
// ---------------------------------------------------------------------------
__global__ __launch_bounds__(256) void qlstm_projx(const float* __restrict__ x,
                                                   const float* __restrict__ Wp,
                                                   float* __restrict__ px) {
    const int wave = threadIdx.x >> 6;
    const int lane = threadIdx.x & 63;
    const int row  = blockIdx.x * 4 + wave;   // row = t*BATCH + b
    const int q    = lane >> 3;
    const int c8   = lane & 7;

    const float4* xr = reinterpret_cast<const float4*>(x  + (size_t)row * DIN + c8 * 32);
    const float4* wr = reinterpret_cast<const float4*>(Wp + q * WPLD + c8 * 32);
    float acc = 0.f;
#pragma unroll
    for (int k = 0; k < 8; ++k) {
        float4 xv = xr[k];
        float4 wv = wr[k];
        acc += xv.x * wv.x + xv.y * wv.y + xv.z * wv.z + xv.w * wv.w;
    }
    // reduce over the 8 lanes sharing this q (xor masks 1,2,4 stay in-group)
    acc += __shfl_xor(acc, 1);
    acc += __shfl_xor(acc, 2);
    acc += __shfl_xor(acc, 4);
    if (c8 == 0) {
        const int b = row & (BATCH - 1);
        const int t = row >> 7;
        px[(size_t)b * (T_STEPS * 8) + t * 8 + q] = acc;   // layout [b][t][q]
    }
}

// ---------------------------------------------------------------------------
// Kernel 2: the sequential recurrence. One block per batch row; no cross-block
// sync needed (recurrence is independent per b). 256 threads.
// Closed-form quantum layer: with cw = cos(proj[b,w] + q_params[w]),
//   q_out[0]   = c1*c2*c3*c4*c5*c6*c7
//   q_out[q>=1]= c0*c1*...*cq
// ---------------------------------------------------------------------------
__global__ __launch_bounds__(256) void qlstm_seq(const float* __restrict__ hx,
                                                 const float* __restrict__ cx,
                                                 const float* __restrict__ Wp,
                                                 const float* __restrict__ qp,
                                                 const float* __restrict__ Wg,
                                                 const float* __restrict__ bg,
                                                 const float* __restrict__ px,
                                                 float* __restrict__ out) {
    __shared__ float px_lds[T_STEPS * 8];   // 16 KB: all proj_x for this b
    __shared__ float h_lds[HID];
    __shared__ float cq_lds[8];
    __shared__ float qp_lds[8];

    const int tid = threadIdx.x;
    const int b   = blockIdx.x;
    const int q   = tid >> 5;      // 8 groups of 32 threads, group q owns proj_h[q]
    const int sub = tid & 31;

    // Wp h-part column weights for this thread's 8 h-elements (group q)
    float wph[8];
#pragma unroll
    for (int k = 0; k < 8; ++k) wph[k] = Wp[q * WPLD + DIN + sub * 8 + k];

    // Wg rows tid, 256+tid, 512+tid, 768+tid (8 floats each) -> registers
    const float4* WG4 = reinterpret_cast<const float4*>(Wg);
    const float4 wf0 = WG4[(0 * HID + tid) * 2], wf1 = WG4[(0 * HID + tid) * 2 + 1];
    const float4 wi0 = WG4[(1 * HID + tid) * 2], wi1 = WG4[(1 * HID + tid) * 2 + 1];
    const float4 wg0 = WG4[(2 * HID + tid) * 2], wg1 = WG4[(2 * HID + tid) * 2 + 1];
    const float4 wo0 = WG4[(3 * HID + tid) * 2], wo1 = WG4[(3 * HID + tid) * 2 + 1];
    const float bf  = bg[0 * HID + tid];
    const float bi  = bg[1 * HID + tid];
    const float bgg = bg[2 * HID + tid];
    const float bo  = bg[3 * HID + tid];

    // preload all proj_x for this b into LDS (1024 float4, 4 per thread)
    {
        const float4* P = reinterpret_cast<const float4*>(px + (size_t)b * (T_STEPS * 8));
        float4* L = reinterpret_cast<float4*>(px_lds);
#pragma unroll
        for (int r = 0; r < 4; ++r) L[r * 256 + tid] = P[r * 256 + tid];
    }
    if (tid < 8) qp_lds[tid] = qp[tid];
    h_lds[tid] = hx[b * HID + tid];
    float c  = cx[b * HID + tid];
    float hn = 0.f;
    __syncthreads();

    for (int t = 0; t < T_STEPS; ++t) {
        // proj_h[q] = sum_j h[j] * Wp[q, 256+j]; group q reduces over 32 lanes
        const float4 h0 = *reinterpret_cast<const float4*>(&h_lds[sub * 8]);
        const float4 h1 = *reinterpret_cast<const float4*>(&h_lds[sub * 8 + 4]);
        float p = h0.x * wph[0] + h0.y * wph[1] + h0.z * wph[2] + h0.w * wph[3] +
                  h1.x * wph[4] + h1.y * wph[5] + h1.z * wph[6] + h1.w * wph[7];
        p += __shfl_xor(p, 1);
        p += __shfl_xor(p, 2);
        p += __shfl_xor(p, 4);
        p += __shfl_xor(p, 8);
        p += __shfl_xor(p, 16);
        if (sub == 0) {
            cq_lds[q] = cosf(p + px_lds[t * 8 + q] + qp_lds[q]);
        }
        __syncthreads();   // (A) cq ready; also all h_lds reads of this iter done

        const float c0 = cq_lds[0], c1 = cq_lds[1], c2 = cq_lds[2], c3 = cq_lds[3];
        const float c4 = cq_lds[4], c5 = cq_lds[5], c6 = cq_lds[6], c7 = cq_lds[7];
        const float qo1 = c0 * c1;
        const float qo2 = qo1 * c2;
        const float qo3 = qo2 * c3;
        const float qo4 = qo3 * c4;
        const float qo5 = qo4 * c5;
        const float qo6 = qo5 * c6;
        const float qo7 = qo6 * c7;
        const float qo0 = ((c1 * c2) * (c3 * c4)) * ((c5 * c6) * c7);

        float fg = bf  + qo0 * wf0.x + qo1 * wf0.y + qo2 * wf0.z + qo3 * wf0.w
                       + qo4 * wf1.x + qo5 * wf1.y + qo6 * wf1.z + qo7 * wf1.w;
        float ig = bi  + qo0 * wi0.x + qo1 * wi0.y + qo2 * wi0.z + qo3 * wi0.w
                       + qo4 * wi1.x + qo5 * wi1.y + qo6 * wi1.z + qo7 * wi1.w;
        float gg = bgg + qo0 * wg0.x + qo1 * wg0.y + qo2 * wg0.z + qo3 * wg0.w
                       + qo4 * wg1.x + qo5 * wg1.y + qo6 * wg1.z + qo7 * wg1.w;
        float og = bo  + qo0 * wo0.x + qo1 * wo0.y + qo2 * wo0.z + qo3 * wo0.w
                       + qo4 * wo1.x + qo5 * wo1.y + qo6 * wo1.z + qo7 * wo1.w;

        const float sf = 1.f / (1.f + __expf(-fg));
        const float si = 1.f / (1.f + __expf(-ig));
        const float tg = 1.f - 2.f / (__expf(2.f * gg) + 1.f);   // tanh(g), inf-safe
        const float so = 1.f / (1.f + __expf(-og));
        const float cn = sf * c + si * tg;
        hn = so * (1.f - 2.f / (__expf(2.f * cn) + 1.f));        // so * tanh(cn)

        out[((size_t)t * BATCH + b) * HID + tid] = hn;
        c = cn;
        h_lds[tid] = hn;        // safe: all reads finished before barrier (A)
        __syncthreads();        // (B) h ready for next iteration
    }

    const size_t base = (size_t)T_STEPS * BATCH * HID;
    out[base + b * HID + tid] = hn;                      // h_fin
    out[base + BATCH * HID + b * HID + tid] = c;         // c_fin
}

extern "C" void kernel_launch(void* const* d_in, const int* in_sizes, int n_in,
                              void* d_out, int out_size, void* d_ws, size_t ws_size,
                              hipStream_t stream) {
    const float* x   = (const float*)d_in[0];   // (512,128,256)
    const float* hx  = (const float*)d_in[1];   // (128,256)
    const float* cx  = (const float*)d_in[2];   // (128,256)
    const float* Wp  = (const float*)d_in[3];   // (8,512)
    const float* qp  = (const float*)d_in[4];   // (8,)
    const float* Wg  = (const float*)d_in[5];   // (1024,8)
    const float* bg  = (const float*)d_in[6];   // (1024,)
    float* out = (float*)d_out;
    float* px  = (float*)d_ws;                  // 128*512*8 floats = 2 MB

    qlstm_projx<<<(T_STEPS * BATCH) / 4, 256, 0, stream>>>(x, Wp, px);
    qlstm_seq<<<BATCH, 256, 0, stream>>>(hx, cx, Wp, qp, Wg, bg, px, out);
}

// Round 2
// 413.493 us; speedup vs baseline: 1.2038x; 1.2038x over previous
//
#include <hip/hip_runtime.h>

#ifndef __has_builtin
#define __has_builtin(x) 0
#endif

#define T_STEPS 512
#define BATCH   128
#define DIN     256
#define HID     256
#define WPLD    (DIN + HID)   // 512

// ---------------- cross-lane helpers ----------------
template<int CTRL>
__device__ __forceinline__ float dpp_perm(float x) {
    // quad_perm value permute (VALU-rate). CTRL: 0xB1 = xor1, 0x4E = xor2.
    return __int_as_float(__builtin_amdgcn_update_dpp(0, __float_as_int(x), CTRL, 0xF, 0xF, true));
}
template<int PAT>
__device__ __forceinline__ float swz(float x) {
    // ds_swizzle BitMode: PAT = (xor<<10)|0x1F. 0x101F=xor4, 0x201F=xor8, 0x401F=xor16.
    return __int_as_float(__builtin_amdgcn_ds_swizzle(__float_as_int(x), PAT));
}
__device__ __forceinline__ float rcp_f(float x) {
#if __has_builtin(__builtin_amdgcn_rcpf)
    return __builtin_amdgcn_rcpf(x);
#else
    return 1.0f / x;
#endif
}

// fused LSTM pointwise: 5 exp + 2 rcp per element
__device__ __forceinline__ void lstm_elem(float f, float i, float g, float o,
                                          float& c, float& h) {
    float a  = __expf(-f);            // sf = 1/(1+a)
    float bb = __expf(-i);            // si = 1/(1+bb)
    float d  = __expf(2.f * g);       // tanh(g) = (d-1)/(d+1)
    float num = c * (1.f + bb) * (d + 1.f) + (d - 1.f) * (1.f + a);
    float den = (1.f + a) * (1.f + bb) * (d + 1.f);
    float cn  = num * rcp_f(den);
    float cnc = fminf(fmaxf(cn, -15.f), 15.f);   // guard tanh against overflow only
    float u   = __expf(2.f * cnc);
    float eo  = __expf(-o);
    h = (u - 1.f) * rcp_f((1.f + eo) * (u + 1.f));
    c = cn;
}

// ---------------------------------------------------------------------------
// Kernel 1: px[b][t][q] = sum_d x[t,b,d]*Wp[q,d]  + qp[q]   (qp folded in)
// One wave per row; 1 float4/lane of x; DPP+swizzle reduce (no redundant loads).
// ---------------------------------------------------------------------------
__global__ __launch_bounds__(256) void qlstm_projx(const float* __restrict__ x,
                                                   const float* __restrict__ Wp,
                                                   const float* __restrict__ qp,
                                                   float* __restrict__ px) {
    const int wave = threadIdx.x >> 6;
    const int lane = threadIdx.x & 63;
    const int row  = blockIdx.x * 4 + wave;       // row = t*BATCH + b

    const float4 xv = ((const float4*)(x + (size_t)row * DIN))[lane];
    float acc[8];
#pragma unroll
    for (int Q = 0; Q < 8; ++Q) {
        float4 w = ((const float4*)(Wp + Q * WPLD))[lane];
        acc[Q] = xv.x * w.x + xv.y * w.y + xv.z * w.z + xv.w * w.w;
    }
#pragma unroll
    for (int Q = 0; Q < 8; ++Q) {
        acc[Q] += dpp_perm<0xB1>(acc[Q]);
        acc[Q] += dpp_perm<0x4E>(acc[Q]);
        acc[Q] += swz<0x101F>(acc[Q]);
    }
    float p = acc[0];
#pragma unroll
    for (int j = 1; j < 8; ++j) p = ((lane & 7) == j) ? acc[j] : p;
    p += swz<0x201F>(p);
    p += swz<0x401F>(p);
    p += __shfl_xor(p, 32);
    if (lane < 8) {
        const int bb = row & (BATCH - 1);
        const int tt = row >> 7;
        px[(size_t)bb * (T_STEPS * 8) + tt * 8 + lane] = p + qp[lane];
    }
}

// ---------------------------------------------------------------------------
// Kernel 2: recurrence. ONE WAVE per batch row — zero barriers.
// h stored XOR-swizzled in LDS (f4 slot s -> s^(s>>3)) => conflict-free gather.
// Closed-form quantum layer; all Wg/Wph/bg in registers.
// ---------------------------------------------------------------------------
__global__ __launch_bounds__(64, 1) void qlstm_seq(const float* __restrict__ hx,
                                                   const float* __restrict__ cx,
                                                   const float* __restrict__ Wp,
                                                   const float* __restrict__ Wg,
                                                   const float* __restrict__ bg,
                                                   const float* __restrict__ px,
                                                   float* __restrict__ out) {
    __shared__ float  px_lds[T_STEPS * 8];   // 16 KB
    __shared__ float4 h_lds[64];             // 1 KB, swizzled

    const int l = threadIdx.x;
    const int b = blockIdx.x;
    const int q = l >> 3;
    const int m = l & 7;

    // preload all px for this b (qp already folded in)
    {
        const float4* pg = (const float4*)(px + (size_t)b * (T_STEPS * 8));
        float4* pl = (float4*)px_lds;
#pragma unroll
        for (int j = 0; j < 16; ++j) pl[j * 64 + l] = pg[j * 64 + l];
    }

    // proj-h weights: Wp[q][256 + 32m .. +31]
    float4 wph[8];
    {
        const float4* wr = (const float4*)(Wp + q * WPLD + DIN + m * 32);
#pragma unroll
        for (int k = 0; k < 8; ++k) wph[k] = wr[k];
    }

    // gate weights+bias: rows G*256 + 4l + e
    float wg[4][4][8];
    float bgr[4][4];
#pragma unroll
    for (int G = 0; G < 4; ++G)
#pragma unroll
        for (int e = 0; e < 4; ++e) {
            const float4* r2 = (const float4*)(Wg + (size_t)(G * HID + 4 * l + e) * 8);
            float4 lo = r2[0], hi = r2[1];
            wg[G][e][0] = lo.x; wg[G][e][1] = lo.y; wg[G][e][2] = lo.z; wg[G][e][3] = lo.w;
            wg[G][e][4] = hi.x; wg[G][e][5] = hi.y; wg[G][e][6] = hi.z; wg[G][e][7] = hi.w;
            bgr[G][e] = bg[G * HID + 4 * l + e];
        }

    // init state
    float4 hv = *(const float4*)(hx + b * HID + 4 * l);
    h_lds[l ^ (l >> 3)] = hv;
    float4 cv = *(const float4*)(cx + b * HID + 4 * l);
    float cc[4] = {cv.x, cv.y, cv.z, cv.w};
    float4 hnew = hv;

    float* outp = out + (size_t)b * HID + 4 * l;

    for (int t = 0; t < T_STEPS; ++t) {
        const float pxv = px_lds[t * 8 + q];

        // gather 32 h values (logical f4 slots 8m..8m+7, bank-conflict-free)
        float a0 = 0.f, a1 = 0.f, a2 = 0.f, a3 = 0.f;
#pragma unroll
        for (int k = 0; k < 8; ++k) {
            float4 h4 = h_lds[(8 * m + k) ^ m];
            a0 = fmaf(h4.x, wph[k].x, a0);
            a1 = fmaf(h4.y, wph[k].y, a1);
            a2 = fmaf(h4.z, wph[k].z, a2);
            a3 = fmaf(h4.w, wph[k].w, a3);
        }
        float p = (a0 + a1) + (a2 + a3);

        // reduce over the 8 lanes of group q: xor1,xor2 (DPP) + xor4 (swizzle)
        p += dpp_perm<0xB1>(p);
        p += dpp_perm<0x4E>(p);
        p += swz<0x101F>(p);

        const float cw = __cosf(p + pxv);    // cos(2*theta_q)

        // collect all 8 cw into every lane (in-register butterfly)
        float o8 = swz<0x201F>(cw);
        float x0 = (l & 8) ? o8 : cw;
        float x1 = (l & 8) ? cw : o8;
        float y0 = swz<0x401F>(x0), y1 = swz<0x401F>(x1);
        float b0 = (l & 16) ? y0 : x0;
        float b1 = (l & 16) ? y1 : x1;
        float b2 = (l & 16) ? x0 : y0;
        float b3 = (l & 16) ? x1 : y1;
        float z0 = __shfl_xor(b0, 32), z1 = __shfl_xor(b1, 32);
        float z2 = __shfl_xor(b2, 32), z3 = __shfl_xor(b3, 32);
        const float C0 = (l & 32) ? z0 : b0;
        const float C1 = (l & 32) ? z1 : b1;
        const float C2 = (l & 32) ? z2 : b2;
        const float C3 = (l & 32) ? z3 : b3;
        const float C4 = (l & 32) ? b0 : z0;
        const float C5 = (l & 32) ? b1 : z1;
        const float C6 = (l & 32) ? b2 : z2;
        const float C7 = (l & 32) ? b3 : z3;

        // prefix products (tree):  qo[0]=c1..c7, qo[k>=1]=c0..ck
        const float d01 = C0 * C1, d23 = C2 * C3, d45 = C4 * C5, d67 = C6 * C7;
        float qo[8];
        qo[1] = d01;
        qo[2] = d01 * C2;
        qo[3] = d01 * d23;
        qo[4] = qo[3] * C4;
        qo[5] = qo[3] * d45;
        qo[6] = qo[5] * C6;
        qo[7] = qo[5] * d67;
        qo[0] = (C1 * d23) * (d45 * d67);

        // gates (all weights in registers)
        float gf[4], gi[4], gg[4], go[4];
#pragma unroll
        for (int e = 0; e < 4; ++e) {
            float af = bgr[0][e], ai = bgr[1][e], ag = bgr[2][e], ao = bgr[3][e];
#pragma unroll
            for (int j = 0; j < 8; ++j) {
                af = fmaf(wg[0][e][j], qo[j], af);
                ai = fmaf(wg[1][e][j], qo[j], ai);
                ag = fmaf(wg[2][e][j], qo[j], ag);
                ao = fmaf(wg[3][e][j], qo[j], ao);
            }
            gf[e] = af; gi[e] = ai; gg[e] = ag; go[e] = ao;
        }

        float h0, h1, h2, h3;
        lstm_elem(gf[0], gi[0], gg[0], go[0], cc[0], h0);
        lstm_elem(gf[1], gi[1], gg[1], go[1], cc[1], h1);
        lstm_elem(gf[2], gi[2], gg[2], go[2], cc[2], h2);
        lstm_elem(gf[3], gi[3], gg[3], go[3], cc[3], h3);

        hnew = make_float4(h0, h1, h2, h3);
        *(float4*)outp = hnew;
        outp += BATCH * HID;
        h_lds[l ^ (l >> 3)] = hnew;   // wave-ordered LDS: safe without barrier
    }

    const size_t base = (size_t)T_STEPS * BATCH * HID;
    *(float4*)(out + base + b * HID + 4 * l) = hnew;
    *(float4*)(out + base + BATCH * HID + b * HID + 4 * l) = make_float4(cc[0], cc[1], cc[2], cc[3]);
}

extern "C" void kernel_launch(void* const* d_in, const int* in_sizes, int n_in,
                              void* d_out, int out_size, void* d_ws, size_t ws_size,
                              hipStream_t stream) {
    const float* x   = (const float*)d_in[0];   // (512,128,256)
    const float* hx  = (const float*)d_in[1];   // (128,256)
    const float* cx  = (const float*)d_in[2];   // (128,256)
    const float* Wp  = (const float*)d_in[3];   // (8,512)
    const float* qp  = (const float*)d_in[4];   // (8,)
    const float* Wg  = (const float*)d_in[5];   // (1024,8)
    const float* bg  = (const float*)d_in[6];   // (1024,)
    float* out = (float*)d_out;
    float* px  = (float*)d_ws;                  // 128*512*8 floats = 2 MB

    qlstm_projx<<<(T_STEPS * BATCH) / 4, 256, 0, stream>>>(x, Wp, qp, px);
    qlstm_seq<<<BATCH, 64, 0, stream>>>(hx, cx, Wp, Wg, bg, px, out);
}